// Round 7
// baseline (156.905 us; speedup 1.0000x reference)
//
#include <hip/hip_runtime.h>
#include <hip/hip_bf16.h>

#define D 128            // D_IN == D_OUT
#define D2U 64           // D/2 packed bf16 pairs (uint) per row

typedef __attribute__((ext_vector_type(8))) short  short8;
typedef __attribute__((ext_vector_type(4))) float  f32x4;
typedef __attribute__((ext_vector_type(2))) float  f32x2;

// fp32 -> bf16 (RTNE)
__device__ __forceinline__ unsigned f2bf(float f) {
    unsigned u = __float_as_uint(f);
    u += 0x7FFFu + ((u >> 16) & 1u);
    return u >> 16;
}
__device__ __forceinline__ unsigned pk2(float a, float b) {
    return f2bf(a) | (f2bf(b) << 16);
}
__device__ __forceinline__ float bflo(unsigned u) { return __uint_as_float(u << 16); }
__device__ __forceinline__ float bfhi(unsigned u) { return __uint_as_float(u & 0xFFFF0000u); }

// ---------------------------------------------------------------------------
// Kernel 1: y = bf16(x @ W) via MFMA 16x16x32 bf16.  (unchanged)
// ---------------------------------------------------------------------------
__global__ __launch_bounds__(256, 2) void gemm_mfma_kernel(
    const float* __restrict__ x, const float* __restrict__ W,
    unsigned* __restrict__ y, int n_nodes, int ntiles)
{
    __shared__ unsigned short Wt[D * D];   // bf16 [c][k], k XOR-swizzled, 32 KB

    const int t = threadIdx.x;

    {
        const float4* W4 = reinterpret_cast<const float4*>(W);
#pragma unroll
        for (int m = 0; m < 16; ++m) {
            const int idx4 = m * 256 + t;        // float4 index
            const int k  = idx4 >> 5;            // 32 float4 per k-row
            const int c0 = (idx4 & 31) << 2;
            const float4 w = W4[idx4];
            const float wv[4] = {w.x, w.y, w.z, w.w};
#pragma unroll
            for (int i = 0; i < 4; ++i) {
                const int c    = c0 + i;
                const int slot = (k >> 3) ^ (c & 15);
                Wt[c * 128 + slot * 8 + (k & 7)] = (unsigned short)f2bf(wv[i]);
            }
        }
    }
    __syncthreads();

    const int lane = t & 63;
    const int cl   = lane & 15;
    const int g    = lane >> 4;

    short8 wf[8][4];
#pragma unroll
    for (int ct = 0; ct < 8; ++ct)
#pragma unroll
        for (int ks = 0; ks < 4; ++ks) {
            const int c    = ct * 16 + cl;
            const int slot = (ks * 4 + g) ^ cl;
            wf[ct][ks] = *reinterpret_cast<const short8*>(&Wt[c * 128 + slot * 8]);
        }

    const int wave   = (blockIdx.x << 2) | (t >> 6);
    const int nwaves = gridDim.x << 2;

#define LOADX(rt_, buf_)                                                      \
    {                                                                         \
        int r_ = (rt_) * 16 + cl;                                             \
        if (r_ >= n_nodes) r_ = n_nodes - 1;                                  \
        const float* p_ = x + (size_t)r_ * D + g * 8;                         \
        _Pragma("unroll")                                                     \
        for (int ks_ = 0; ks_ < 4; ++ks_) {                                   \
            buf_[2 * ks_]     = *reinterpret_cast<const float4*>(p_ + ks_ * 32);     \
            buf_[2 * ks_ + 1] = *reinterpret_cast<const float4*>(p_ + ks_ * 32 + 4); \
        }                                                                     \
    }

#define COMPUTE(rt_, buf_)                                                    \
    {                                                                         \
        f32x4 acc_[8];                                                        \
        _Pragma("unroll")                                                     \
        for (int ct_ = 0; ct_ < 8; ++ct_) acc_[ct_] = (f32x4)(0.f);           \
        _Pragma("unroll")                                                     \
        for (int ks_ = 0; ks_ < 4; ++ks_) {                                   \
            short8 xf_;                                                       \
            unsigned* xu_ = reinterpret_cast<unsigned*>(&xf_);                \
            const float4 a_ = buf_[2 * ks_], b_ = buf_[2 * ks_ + 1];          \
            xu_[0] = pk2(a_.x, a_.y); xu_[1] = pk2(a_.z, a_.w);               \
            xu_[2] = pk2(b_.x, b_.y); xu_[3] = pk2(b_.z, b_.w);               \
            _Pragma("unroll")                                                 \
            for (int ct_ = 0; ct_ < 8; ++ct_)                                 \
                acc_[ct_] = __builtin_amdgcn_mfma_f32_16x16x32_bf16(          \
                    wf[ct_][ks_], xf_, acc_[ct_], 0, 0, 0);                   \
        }                                                                     \
        const int r_ = (rt_) * 16 + cl;                                       \
        if (r_ < n_nodes) {                                                   \
            unsigned* yp_ = y + (size_t)r_ * D2U + g * 2;                     \
            _Pragma("unroll")                                                 \
            for (int ct_ = 0; ct_ < 8; ++ct_) {                               \
                uint2 v2_ = make_uint2(pk2(acc_[ct_][0], acc_[ct_][1]),       \
                                       pk2(acc_[ct_][2], acc_[ct_][3]));      \
                *reinterpret_cast<uint2*>(yp_ + ct_ * 8) = v2_;               \
            }                                                                 \
        }                                                                     \
    }

    int rt = wave;
    if (rt >= ntiles) return;
    float4 bufA[8], bufB[8];
    LOADX(rt, bufA);
    while (true) {
        int nxt = rt + nwaves;
        if (nxt < ntiles) {
            LOADX(nxt, bufB);
            COMPUTE(rt, bufA);
            rt = nxt;
            nxt = rt + nwaves;
            if (nxt < ntiles) {
                LOADX(nxt, bufA);
                COMPUTE(rt, bufB);
                rt = nxt;
            } else { COMPUTE(rt, bufB); break; }
        } else { COMPUTE(rt, bufA); break; }
    }
#undef LOADX
#undef COMPUTE
}

// ---------------------------------------------------------------------------
// Kernel 2: build CSR row_ptr from sorted edge_row.
// ---------------------------------------------------------------------------
__global__ __launch_bounds__(256) void build_rowptr_kernel(
    const int* __restrict__ row, int* __restrict__ ptr, int n_edges, int n_nodes)
{
    int e = blockIdx.x * blockDim.x + threadIdx.x;
    if (e > n_edges) return;
    int lo, hi;                     // set ptr[r] = e for r in (lo, hi]
    if (e == 0)            { lo = -1;               hi = row[0];   }
    else if (e == n_edges) { lo = row[n_edges - 1]; hi = n_nodes;  }
    else {
        lo = row[e - 1];
        hi = row[e];
        if (lo == hi) return;
    }
    for (int r = lo + 1; r <= hi; ++r) ptr[r] = e;
}

// ---------------------------------------------------------------------------
// Kernel 3: out[r,:] = sum_e val[e] * y[col[e],:]   (bf16 gather, fp32 acc)
// FOUR rows per wave (quarter q = lane>>4, ql = lane&15); each lane owns a
// uint4 (8 bf16 cols) -> dwordx4 gathers, 1 KB per instruction (4x fewer
// gather instrs than R6). cv loaded as aligned int4/float4, vals PRE-MASKED
// at load (consume loop has no compares). Batch b+1's gathers are issued
// before consuming batch b (cv(b+1) already drained), overlapping consume
// VALU with gather latency. f32x2 accumulators -> v_pk_fma_f32.
// ---------------------------------------------------------------------------
__global__ __launch_bounds__(256) void spmm_kernel(
    const uint4* __restrict__ yb4, const int* __restrict__ ptr,
    const int* __restrict__ col, const float* __restrict__ val,
    float4* __restrict__ out4, int n_nodes, int n_edges)
{
    const int gid  = blockIdx.x * blockDim.x + threadIdx.x;
    const int w    = gid >> 6;
    const int lane = threadIdx.x & 63;
    const int q    = lane >> 4;          // quarter-row 0..3
    const int ql   = lane & 15;
    const int row  = (w << 2) + q;
    const bool valid = (row < n_nodes);

    int s = 0, e = 0;
    if (valid) { s = ptr[row]; e = ptr[row + 1]; }

    const int base = s & ~3;             // 16B-aligned batch grid
    const int nb   = valid ? ((e - base + 3) >> 2) : 0;

    f32x2 a0 = {0.f, 0.f}, a1 = {0.f, 0.f}, a2 = {0.f, 0.f}, a3 = {0.f, 0.f};

    int4   C0, C1;
    float4 V0, V1;
    uint4  U[4], T[4];

    // load cv batch b_, vals pre-masked to 0 outside [s,e)
#define CVLOAD(b_, C_, V_)                                                   \
    {                                                                        \
        const int o_ = base + ((b_) << 2);                                   \
        if (o_ + 4 <= n_edges) {                                             \
            C_ = *reinterpret_cast<const int4*>(col + o_);                   \
            V_ = *reinterpret_cast<const float4*>(val + o_);                 \
        } else {                                                             \
            const int m_ = n_edges - 1;                                      \
            C_.x = col[min(o_ + 0, m_)]; C_.y = col[min(o_ + 1, m_)];        \
            C_.z = col[min(o_ + 2, m_)]; C_.w = col[min(o_ + 3, m_)];        \
            V_.x = val[min(o_ + 0, m_)]; V_.y = val[min(o_ + 1, m_)];        \
            V_.z = val[min(o_ + 2, m_)]; V_.w = val[min(o_ + 3, m_)];        \
        }                                                                    \
        V_.x = (o_ + 0 >= s && o_ + 0 < e) ? V_.x : 0.f;                     \
        V_.y = (o_ + 1 >= s && o_ + 1 < e) ? V_.y : 0.f;                     \
        V_.z = (o_ + 2 >= s && o_ + 2 < e) ? V_.z : 0.f;                     \
        V_.w = (o_ + 3 >= s && o_ + 3 < e) ? V_.w : 0.f;                     \
    }

#define GATHER(C_, U_)                                                       \
    {                                                                        \
        U_[0] = yb4[(size_t)C_.x * 16 + ql];                                 \
        U_[1] = yb4[(size_t)C_.y * 16 + ql];                                 \
        U_[2] = yb4[(size_t)C_.z * 16 + ql];                                 \
        U_[3] = yb4[(size_t)C_.w * 16 + ql];                                 \
    }

#define CONSUME1(u_, v_)                                                     \
    {                                                                        \
        f32x2 vv_; vv_.x = (v_); vv_.y = (v_);                               \
        f32x2 t_;                                                            \
        t_.x = bflo(u_.x); t_.y = bfhi(u_.x); a0 += vv_ * t_;                \
        t_.x = bflo(u_.y); t_.y = bfhi(u_.y); a1 += vv_ * t_;                \
        t_.x = bflo(u_.z); t_.y = bfhi(u_.z); a2 += vv_ * t_;                \
        t_.x = bflo(u_.w); t_.y = bfhi(u_.w); a3 += vv_ * t_;                \
    }
#define CONSUME(U_, V_)                                                      \
    {                                                                        \
        CONSUME1(U_[0], V_.x); CONSUME1(U_[1], V_.y);                        \
        CONSUME1(U_[2], V_.z); CONSUME1(U_[3], V_.w);                        \
    }

    // iteration: on entry Ua = gathers(b) in flight, (Cb,Vb) = cv(b+1) in
    // flight, Va = masked vals(b). Issue gathers(b+1) BEFORE consuming b.
#define ITER(b_, Ca_, Va_, Cb_, Vb_, Ua_, Ub_)                               \
    {                                                                        \
        if ((b_) + 1 < nb) GATHER(Cb_, Ub_);                                 \
        CONSUME(Ua_, Va_);                                                   \
        if ((b_) + 2 < nb) CVLOAD((b_) + 2, Ca_, Va_);                       \
    }

    if (nb > 0) {
        CVLOAD(0, C0, V0);
        GATHER(C0, U);
        if (nb > 1) CVLOAD(1, C1, V1);

        int b = 0;
        while (true) {
            ITER(b, C0, V0, C1, V1, U, T);
            if (++b >= nb) break;
            ITER(b, C1, V1, C0, V0, T, U);
            if (++b >= nb) break;
        }
    }
#undef CVLOAD
#undef GATHER
#undef CONSUME1
#undef CONSUME
#undef ITER

    if (valid) {
        f32x4 o1, o2;
        o1.x = a0.x; o1.y = a0.y; o1.z = a1.x; o1.w = a1.y;
        o2.x = a2.x; o2.y = a2.y; o2.z = a3.x; o2.w = a3.y;
        f32x4* op = reinterpret_cast<f32x4*>(out4 + (size_t)row * 32 + (ql << 1));
        __builtin_nontemporal_store(o1, op);
        __builtin_nontemporal_store(o2, op + 1);
    }
}

// ---------------------------------------------------------------------------
extern "C" void kernel_launch(void* const* d_in, const int* in_sizes, int n_in,
                              void* d_out, int out_size, void* d_ws, size_t ws_size,
                              hipStream_t stream)
{
    const float* x        = (const float*)d_in[0];
    const int*   edge_row = (const int*)  d_in[1];
    const int*   edge_col = (const int*)  d_in[2];
    const float* edge_val = (const float*)d_in[3];
    const float* W        = (const float*)d_in[4];
    float*       out      = (float*)d_out;

    const int n_nodes = in_sizes[0] / D;
    const int n_edges = in_sizes[1];
    const int ntiles  = (n_nodes + 15) / 16;

    // workspace layout: y_bf16 [n_nodes*D2U uint] | row_ptr [(n_nodes+1) i32]
    unsigned* y   = (unsigned*)d_ws;
    int*      ptr = (int*)((char*)d_ws + (size_t)n_nodes * D2U * sizeof(unsigned));

    // 1) y = bf16(x @ W)  (MFMA)
    gemm_mfma_kernel<<<512, 256, 0, stream>>>(x, W, y, n_nodes, ntiles);

    // 2) row_ptr
    {
        int blocks = (n_edges + 1 + 255) / 256;
        build_rowptr_kernel<<<blocks, 256, 0, stream>>>(edge_row, ptr, n_edges, n_nodes);
    }
    // 3) out = A @ y   (four rows per wave)
    {
        int nwaves = (n_nodes + 3) / 4;
        int blocks = (nwaves + 3) / 4;          // 4 waves per 256-thread block
        spmm_kernel<<<blocks, 256, 0, stream>>>((const uint4*)y, ptr,
                                                edge_col, edge_val,
                                                (float4*)out, n_nodes, n_edges);
    }
}